// Round 3
// baseline (182.507 us; speedup 1.0000x reference)
//
#include <hip/hip_runtime.h>

typedef __attribute__((ext_vector_type(8))) short short8;
typedef __attribute__((ext_vector_type(4))) float f32x4;
typedef __attribute__((ext_vector_type(4))) unsigned short u16x4;
typedef unsigned short u16;

#define Bn 8
#define Tn 2048
#define Cn 1024
#define Hn 64
#define Mrows (Bn * Tn)  // 16384

__device__ __forceinline__ u16 f2bf(float f) {
    union { float f; unsigned u; } c; c.f = f;
    unsigned u = c.u;
    unsigned r = (u + 0x7fffu + ((u >> 16) & 1u)) >> 16;
    return (u16)r;
}

// All three W [1024][64] f32 -> wt [3][64][1024] bf16 (transposed), scale folded.
__global__ void convert_w3(const float* __restrict__ Wq, const float* __restrict__ Wk,
                           const float* __restrict__ Wv, u16* __restrict__ wt, float qscale) {
    int widx = blockIdx.x * 256 + threadIdx.x;          // 0 .. 3*65536-1
    int mat = widx >> 16;
    int rem = widx & 65535;
    int k = rem >> 6, n = rem & 63;
    const float* W = mat == 0 ? Wq : (mat == 1 ? Wk : Wv);
    float s = mat == 0 ? qscale : 1.0f;
    wt[(size_t)mat * 65536 + n * Cn + k] = f2bf(W[rem] * s);
}

// x [16384][1024] f32 @ wt^T -> q,k bf16 [16384][64] + vt bf16 [8][64][2048].
// Block: 32 rows x 192 cols, 8 waves (2M x 4N), BK=128. Grid 512 = 2 blocks/CU.
__global__ __launch_bounds__(512) void qkv_proj(const float* __restrict__ x,
                                                const u16* __restrict__ wt,
                                                u16* __restrict__ qk,
                                                u16* __restrict__ vt) {
    __shared__ u16 xs[32][136];  // BK=128 + 8 pad
    const int tid = threadIdx.x;
    const int lane = tid & 63;
    const int wid = tid >> 6;
    const int wm = wid >> 2;   // 0..1 -> 16-row slice
    const int wn = wid & 3;    // 0..3 -> 48-col slice
    const int row0 = blockIdx.x * 32;
    const int l15 = lane & 15;
    const int lhi = lane >> 4;
    const int trow = tid >> 4;        // 0..31
    const int tk8 = (tid & 15) * 8;   // 0..120

    f32x4 acc[3];
    for (int j = 0; j < 3; ++j) acc[j] = f32x4{0.f, 0.f, 0.f, 0.f};

    for (int ko = 0; ko < Cn; ko += 128) {
        __syncthreads();
        const float* src = x + (size_t)(row0 + trow) * Cn + ko + tk8;
        f32x4 a0 = *(const f32x4*)(src);
        f32x4 a1 = *(const f32x4*)(src + 4);
        short8 pack;
        pack[0] = (short)f2bf(a0[0]); pack[1] = (short)f2bf(a0[1]);
        pack[2] = (short)f2bf(a0[2]); pack[3] = (short)f2bf(a0[3]);
        pack[4] = (short)f2bf(a1[0]); pack[5] = (short)f2bf(a1[1]);
        pack[6] = (short)f2bf(a1[2]); pack[7] = (short)f2bf(a1[3]);
        *(short8*)&xs[trow][tk8] = pack;
        __syncthreads();

        for (int kc = 0; kc < 4; ++kc) {
            short8 af = *(const short8*)&xs[wm * 16 + l15][kc * 32 + lhi * 8];
            for (int nj = 0; nj < 3; ++nj) {
                int gcol = wn * 48 + nj * 16 + l15;
                short8 bf = *(const short8*)(wt + (size_t)gcol * Cn + ko + kc * 32 + lhi * 8);
                acc[nj] = __builtin_amdgcn_mfma_f32_16x16x32_bf16(af, bf, acc[nj], 0, 0, 0);
            }
        }
    }
    const int growb = row0 + wm * 16 + lhi * 4;
    for (int nj = 0; nj < 3; ++nj) {
        int gcolb = wn * 48 + nj * 16 + l15;
        int mat = gcolb >> 6, lcol = gcolb & 63;
        if (mat < 2) {
            u16* dst = qk + (size_t)mat * (Mrows * Hn);
            for (int r = 0; r < 4; ++r)
                dst[(size_t)(growb + r) * Hn + lcol] = f2bf(acc[nj][r]);
        } else {
            // V transposed: vt[b][d][t]; 4 consecutive t -> one 8B store
            int b = growb >> 11, t = growb & 2047;
            u16x4 pk;
            pk[0] = f2bf(acc[nj][0]); pk[1] = f2bf(acc[nj][1]);
            pk[2] = f2bf(acc[nj][2]); pk[3] = f2bf(acc[nj][3]);
            *(u16x4*)(vt + ((size_t)b * Hn + lcol) * Tn + t) = pk;
        }
    }
}

// Flash attention, causal. One wave per 16 q-rows. k-tiles of 64.
// Scale (C^-0.5 * log2e) folded into q. V is pre-transposed (vt[b][d][t]).
__global__ __launch_bounds__(64) void attn_fwd(const u16* __restrict__ q,
                                               const u16* __restrict__ k,
                                               const u16* __restrict__ vt,
                                               float* __restrict__ out) {
    __shared__ u16 pl[16][72];
    const int lane = threadIdx.x;
    const int l15 = lane & 15, lhi = lane >> 4;
    const int b = blockIdx.y;
    const int qt = (int)(gridDim.x - 1) - (int)blockIdx.x;  // longest first
    const int q0 = qt * 16;
    const u16* qb = q + (size_t)b * Tn * Hn;
    const u16* kbp = k + (size_t)b * Tn * Hn;
    const u16* vtb = vt + (size_t)b * Hn * Tn;

    short8 qf[2];
    for (int kc = 0; kc < 2; ++kc)
        qf[kc] = *(const short8*)(qb + (size_t)(q0 + l15) * Hn + kc * 32 + lhi * 8);

    float m[4], ssum[4];
    f32x4 o[4];
    for (int r = 0; r < 4; ++r) { m[r] = -1e30f; ssum[r] = 0.f; }
    for (int dt = 0; dt < 4; ++dt) o[dt] = f32x4{0.f, 0.f, 0.f, 0.f};

    const int nkt = (q0 >> 6) + 1;
    for (int kbi = 0; kbi < nkt; ++kbi) {
        const int k0 = kbi * 64;
        f32x4 sacc[4];
        for (int kt = 0; kt < 4; ++kt) sacc[kt] = f32x4{0.f, 0.f, 0.f, 0.f};
        for (int kc = 0; kc < 2; ++kc) {
            for (int kt = 0; kt < 4; ++kt) {
                short8 kf = *(const short8*)(kbp + (size_t)(k0 + kt * 16 + l15) * Hn + kc * 32 + lhi * 8);
                sacc[kt] = __builtin_amdgcn_mfma_f32_16x16x32_bf16(qf[kc], kf, sacc[kt], 0, 0, 0);
            }
        }
        if (kbi == nkt - 1) {  // diagonal tile: causal mask
            for (int kt = 0; kt < 4; ++kt)
                for (int r = 0; r < 4; ++r) {
                    int kg = k0 + kt * 16 + l15;
                    int qg = q0 + lhi * 4 + r;
                    if (kg > qg) sacc[kt][r] = -1e30f;
                }
        }
        for (int r = 0; r < 4; ++r) {
            float tmax = fmaxf(fmaxf(sacc[0][r], sacc[1][r]), fmaxf(sacc[2][r], sacc[3][r]));
            tmax = fmaxf(tmax, __shfl_xor(tmax, 1));
            tmax = fmaxf(tmax, __shfl_xor(tmax, 2));
            tmax = fmaxf(tmax, __shfl_xor(tmax, 4));
            tmax = fmaxf(tmax, __shfl_xor(tmax, 8));
            float mnew = fmaxf(m[r], tmax);
            float corr = exp2f(m[r] - mnew);
            float psum = 0.f;
            for (int kt = 0; kt < 4; ++kt) {
                float p = exp2f(sacc[kt][r] - mnew);
                sacc[kt][r] = p;
                psum += p;
            }
            psum += __shfl_xor(psum, 1);
            psum += __shfl_xor(psum, 2);
            psum += __shfl_xor(psum, 4);
            psum += __shfl_xor(psum, 8);
            ssum[r] = ssum[r] * corr + psum;
            m[r] = mnew;
            for (int dt = 0; dt < 4; ++dt) o[dt][r] *= corr;
        }
        // P (D-layout) -> LDS -> A-fragment layout. Wave-private: no barrier.
        for (int kt = 0; kt < 4; ++kt)
            for (int r = 0; r < 4; ++r)
                pl[lhi * 4 + r][kt * 16 + l15] = f2bf(sacc[kt][r]);
        short8 pf[2];
        for (int kc = 0; kc < 2; ++kc)
            pf[kc] = *(const short8*)&pl[l15][kc * 32 + lhi * 8];
        // PV: B-fragment = V[k][d] = vt[d][k], contiguous in k
        for (int dt = 0; dt < 4; ++dt) {
            for (int kc = 0; kc < 2; ++kc) {
                short8 vf = *(const short8*)(vtb + (size_t)(dt * 16 + l15) * Tn + k0 + kc * 32 + lhi * 8);
                o[dt] = __builtin_amdgcn_mfma_f32_16x16x32_bf16(pf[kc], vf, o[dt], 0, 0, 0);
            }
        }
    }
    float* ob = out + (size_t)b * Tn * Hn;
    for (int dt = 0; dt < 4; ++dt)
        for (int r = 0; r < 4; ++r)
            ob[(size_t)(q0 + lhi * 4 + r) * Hn + dt * 16 + l15] = o[dt][r] / ssum[r];
}

extern "C" void kernel_launch(void* const* d_in, const int* in_sizes, int n_in,
                              void* d_out, int out_size, void* d_ws, size_t ws_size,
                              hipStream_t stream) {
    const float* x = (const float*)d_in[0];
    const float* Wq = (const float*)d_in[1];
    const float* Wk = (const float*)d_in[2];
    const float* Wv = (const float*)d_in[3];
    float* out = (float*)d_out;
    char* ws = (char*)d_ws;

    u16* wt = (u16*)ws;                                    // [3][64][1024] bf16
    u16* qk = (u16*)(ws + 3 * Hn * Cn * 2);                // 2 x [16384][64] bf16
    u16* vt = qk + 2 * (size_t)Mrows * Hn;                 // [8][64][2048] bf16

    const float qscale = 0.04508422002778011f;  // C^-0.5 * log2(e)
    convert_w3<<<768, 256, 0, stream>>>(Wq, Wk, Wv, wt, qscale);
    qkv_proj<<<512, 512, 0, stream>>>(x, wt, qk, vt);
    attn_fwd<<<dim3(Tn / 16, Bn), 64, 0, stream>>>(
        qk, qk + (size_t)Mrows * Hn, vt, out);
}

// Round 4
// 110.200 us; speedup vs baseline: 1.6561x; 1.6561x over previous
//
#include <hip/hip_runtime.h>

typedef __attribute__((ext_vector_type(8))) short short8;
typedef __attribute__((ext_vector_type(4))) float f32x4;
typedef __attribute__((ext_vector_type(4))) unsigned short u16x4;
typedef unsigned short u16;

#define Bn 8
#define Tn 2048
#define Cn 1024
#define Hn 64
#define Mrows (Bn * Tn)  // 16384
#define UPB 320          // split-K work units per batch
#define SLOTF 1056       // floats per partial slot: 1024 o + 16 m + 16 l

__device__ __forceinline__ u16 f2bf(float f) {
    union { float f; unsigned u; } c; c.f = f;
    unsigned u = c.u;
    unsigned r = (u + 0x7fffu + ((u >> 16) & 1u)) >> 16;
    return (u16)r;
}

// All three W [1024][64] f32 -> wt [3][64][1024] bf16 (transposed), scale folded.
__global__ void convert_w3(const float* __restrict__ Wq, const float* __restrict__ Wk,
                           const float* __restrict__ Wv, u16* __restrict__ wt, float qscale) {
    int widx = blockIdx.x * 256 + threadIdx.x;          // 0 .. 3*65536-1
    int mat = widx >> 16;
    int rem = widx & 65535;
    int k = rem >> 6, n = rem & 63;
    const float* W = mat == 0 ? Wq : (mat == 1 ? Wk : Wv);
    float s = mat == 0 ? qscale : 1.0f;
    wt[(size_t)mat * 65536 + n * Cn + k] = f2bf(W[rem] * s);
}

// x [16384][1024] f32 @ wt^T -> q,k bf16 [16384][64] + vt bf16 [8][64][2048].
__global__ __launch_bounds__(512) void qkv_proj(const float* __restrict__ x,
                                                const u16* __restrict__ wt,
                                                u16* __restrict__ qk,
                                                u16* __restrict__ vt) {
    __shared__ u16 xs[32][136];  // BK=128 + 8 pad
    const int tid = threadIdx.x;
    const int lane = tid & 63;
    const int wid = tid >> 6;
    const int wm = wid >> 2;   // 0..1 -> 16-row slice
    const int wn = wid & 3;    // 0..3 -> 48-col slice
    const int row0 = blockIdx.x * 32;
    const int l15 = lane & 15;
    const int lhi = lane >> 4;
    const int trow = tid >> 4;        // 0..31
    const int tk8 = (tid & 15) * 8;   // 0..120

    f32x4 acc[3];
    for (int j = 0; j < 3; ++j) acc[j] = f32x4{0.f, 0.f, 0.f, 0.f};

    for (int ko = 0; ko < Cn; ko += 128) {
        __syncthreads();
        const float* src = x + (size_t)(row0 + trow) * Cn + ko + tk8;
        f32x4 a0 = *(const f32x4*)(src);
        f32x4 a1 = *(const f32x4*)(src + 4);
        short8 pack;
        pack[0] = (short)f2bf(a0[0]); pack[1] = (short)f2bf(a0[1]);
        pack[2] = (short)f2bf(a0[2]); pack[3] = (short)f2bf(a0[3]);
        pack[4] = (short)f2bf(a1[0]); pack[5] = (short)f2bf(a1[1]);
        pack[6] = (short)f2bf(a1[2]); pack[7] = (short)f2bf(a1[3]);
        *(short8*)&xs[trow][tk8] = pack;
        __syncthreads();

        for (int kc = 0; kc < 4; ++kc) {
            short8 af = *(const short8*)&xs[wm * 16 + l15][kc * 32 + lhi * 8];
            for (int nj = 0; nj < 3; ++nj) {
                int gcol = wn * 48 + nj * 16 + l15;
                short8 bf = *(const short8*)(wt + (size_t)gcol * Cn + ko + kc * 32 + lhi * 8);
                acc[nj] = __builtin_amdgcn_mfma_f32_16x16x32_bf16(af, bf, acc[nj], 0, 0, 0);
            }
        }
    }
    const int growb = row0 + wm * 16 + lhi * 4;
    for (int nj = 0; nj < 3; ++nj) {
        int gcolb = wn * 48 + nj * 16 + l15;
        int mat = gcolb >> 6, lcol = gcolb & 63;
        if (mat < 2) {
            u16* dst = qk + (size_t)mat * (Mrows * Hn);
            for (int r = 0; r < 4; ++r)
                dst[(size_t)(growb + r) * Hn + lcol] = f2bf(acc[nj][r]);
        } else {
            int b = growb >> 11, t = growb & 2047;
            u16x4 pk;
            pk[0] = f2bf(acc[nj][0]); pk[1] = f2bf(acc[nj][1]);
            pk[2] = f2bf(acc[nj][2]); pk[3] = f2bf(acc[nj][3]);
            *(u16x4*)(vt + ((size_t)b * Hn + lcol) * Tn + t) = pk;
        }
    }
}

// Flash attention, causal, split-K. One wave per (16 q-rows, <=512-key chunk).
// Swapped QK^T: lane owns q-row (lane&15), scores lane-local in k.
// Defer-max (THR=8): rescale fires rarely -> 2 shuffles/iter steady state.
// Writes partial (o[16][64], m[16], l[16]) f32 to workspace slot = blockIdx.x.
__global__ __launch_bounds__(64) void attn_fwd(const u16* __restrict__ q,
                                               const u16* __restrict__ k,
                                               const u16* __restrict__ vt,
                                               float* __restrict__ partial) {
    __shared__ u16 pl[16][72];
    const int lane = threadIdx.x;
    const int l15 = lane & 15, lhi = lane >> 4;
    const int bid = blockIdx.x;
    const int b = bid / UPB;
    const int u = bid - b * UPB;
    int qt, c;
    if (u < 32)       { qt = u;                  c = 0; }
    else if (u < 96)  { qt = 32 + ((u - 32) >> 1);  c = (u - 32) & 1; }
    else if (u < 192) { qt = 64 + (u - 96) / 3;     c = (u - 96) % 3; }
    else              { qt = 96 + ((u - 192) >> 2); c = (u - 192) & 3; }
    const int nkt = (qt >> 2) + 1;
    const int kb0 = c * 8;
    const int kbe = min(kb0 + 8, nkt);
    const int q0 = qt * 16;

    const u16* qb = q + (size_t)b * Tn * Hn;
    const u16* kbp = k + (size_t)b * Tn * Hn;
    const u16* vtb = vt + (size_t)b * Hn * Tn;

    short8 qf[2];
    for (int kc = 0; kc < 2; ++kc)
        qf[kc] = *(const short8*)(qb + (size_t)(q0 + l15) * Hn + kc * 32 + lhi * 8);

    float m = -1e30f, lpart = 0.f;   // per-lane: q-row = l15 (uniform across lhi)
    f32x4 o[4];
    for (int dt = 0; dt < 4; ++dt) o[dt] = f32x4{0.f, 0.f, 0.f, 0.f};

    for (int kbi = kb0; kbi < kbe; ++kbi) {
        const int k0 = kbi * 64;
        f32x4 sacc[4];
        for (int kt = 0; kt < 4; ++kt) sacc[kt] = f32x4{0.f, 0.f, 0.f, 0.f};
        // S^T = K·Q^T : D col = q (l15), D row = k-within-tile (lhi*4+r)
        for (int kc = 0; kc < 2; ++kc) {
            for (int kt = 0; kt < 4; ++kt) {
                short8 kf = *(const short8*)(kbp + (size_t)(k0 + kt * 16 + l15) * Hn + kc * 32 + lhi * 8);
                sacc[kt] = __builtin_amdgcn_mfma_f32_16x16x32_bf16(kf, qf[kc], sacc[kt], 0, 0, 0);
            }
        }
        if (kbi == nkt - 1) {  // diagonal tile: causal mask (per-lane, no shuffle)
            for (int kt = 0; kt < 4; ++kt)
                for (int r = 0; r < 4; ++r) {
                    int kg = k0 + kt * 16 + lhi * 4 + r;
                    if (kg > q0 + l15) sacc[kt][r] = -3.0e38f;
                }
        }
        // row max: lane-local over 16, then across the 4 lhi copies
        f32x4 mx0, mx1;
        for (int e = 0; e < 4; ++e) {
            mx0[e] = fmaxf(sacc[0][e], sacc[1][e]);
            mx1[e] = fmaxf(sacc[2][e], sacc[3][e]);
        }
        float tmax = -3.0e38f;
        for (int e = 0; e < 4; ++e) tmax = fmaxf(tmax, fmaxf(mx0[e], mx1[e]));
        tmax = fmaxf(tmax, __shfl_xor(tmax, 16));
        tmax = fmaxf(tmax, __shfl_xor(tmax, 32));
        // defer-max: rescale only when growth exceeds THR=8 (log2 domain)
        if (!__all(tmax <= m + 8.0f)) {
            float mnew = fmaxf(m, tmax);
            float corr = exp2f(m - mnew);
            m = mnew;
            lpart *= corr;
            for (int r = 0; r < 4; ++r) {
                float cr = __shfl(corr, lhi * 4 + r);  // corr for o-row q=lhi*4+r
                for (int dt = 0; dt < 4; ++dt) o[dt][r] *= cr;
            }
        }
        float psum = 0.f;
        for (int kt = 0; kt < 4; ++kt)
            for (int r = 0; r < 4; ++r) {
                float p = exp2f(sacc[kt][r] - m);
                sacc[kt][r] = p;
                psum += p;
            }
        lpart += psum;
        // P -> LDS (packed 4 consecutive k per lane), wave-private
        for (int kt = 0; kt < 4; ++kt) {
            u16x4 pk;
            pk[0] = f2bf(sacc[kt][0]); pk[1] = f2bf(sacc[kt][1]);
            pk[2] = f2bf(sacc[kt][2]); pk[3] = f2bf(sacc[kt][3]);
            *(u16x4*)&pl[l15][kt * 16 + lhi * 4] = pk;
        }
        short8 pf[2];
        for (int kc = 0; kc < 2; ++kc)
            pf[kc] = *(const short8*)&pl[l15][kc * 32 + lhi * 8];
        // O += P·V : vf contiguous in k from vt[d][t]
        for (int dt = 0; dt < 4; ++dt) {
            for (int kc = 0; kc < 2; ++kc) {
                short8 vf = *(const short8*)(vtb + (size_t)(dt * 16 + l15) * Tn + k0 + kc * 32 + lhi * 8);
                o[dt] = __builtin_amdgcn_mfma_f32_16x16x32_bf16(pf[kc], vf, o[dt], 0, 0, 0);
            }
        }
    }
    // l: sum the 4 lhi partial copies
    float lsum = lpart;
    lsum += __shfl_xor(lsum, 16);
    lsum += __shfl_xor(lsum, 32);

    float* ps = partial + (size_t)bid * SLOTF;
    for (int dt = 0; dt < 4; ++dt)
        for (int r = 0; r < 4; ++r)
            ps[(lhi * 4 + r) * 64 + dt * 16 + l15] = o[dt][r];
    if (lhi == 0) {
        ps[1024 + l15] = m;
        ps[1040 + l15] = lsum;
    }
}

// Combine <=4 split-K partials per (b, q-tile): out = sum_c o_c*2^(m_c-M) / sum_c l_c*2^(m_c-M)
__global__ __launch_bounds__(256) void attn_reduce(const float* __restrict__ partial,
                                                   float* __restrict__ out) {
    const int bid = blockIdx.x;           // 0..1023
    const int b = bid >> 7, qt = bid & 127;
    const int nc = qt < 32 ? 1 : qt < 64 ? 2 : qt < 96 ? 3 : 4;
    const int base = b * UPB +
        (qt < 32 ? qt : qt < 64 ? 32 + 2 * (qt - 32)
                      : qt < 96 ? 96 + 3 * (qt - 64) : 192 + 4 * (qt - 96));
    const int d = threadIdx.x & 63;
    const int qr = threadIdx.x >> 6;
    for (int i = 0; i < 4; ++i) {
        const int qq = i * 4 + qr;
        float M = -3.0e38f;
        #pragma unroll
        for (int cc = 0; cc < 4; ++cc)
            if (cc < nc) M = fmaxf(M, partial[(size_t)(base + cc) * SLOTF + 1024 + qq]);
        float L = 0.f, acc = 0.f;
        #pragma unroll
        for (int cc = 0; cc < 4; ++cc)
            if (cc < nc) {
                const float* ps = partial + (size_t)(base + cc) * SLOTF;
                float w = exp2f(ps[1024 + qq] - M);
                L += ps[1040 + qq] * w;
                acc += ps[qq * 64 + d] * w;
            }
        out[((size_t)b * Tn + qt * 16 + qq) * Hn + d] = acc / L;
    }
}

extern "C" void kernel_launch(void* const* d_in, const int* in_sizes, int n_in,
                              void* d_out, int out_size, void* d_ws, size_t ws_size,
                              hipStream_t stream) {
    const float* x = (const float*)d_in[0];
    const float* Wq = (const float*)d_in[1];
    const float* Wk = (const float*)d_in[2];
    const float* Wv = (const float*)d_in[3];
    float* out = (float*)d_out;
    char* ws = (char*)d_ws;

    u16* wt = (u16*)ws;                                    // [3][64][1024] bf16   (384 KB)
    u16* qk = (u16*)(ws + 3 * Hn * Cn * 2);                // 2 x [16384][64] bf16 (4 MB)
    u16* vt = qk + 2 * (size_t)Mrows * Hn;                 // [8][64][2048] bf16   (2 MB)
    float* partial = (float*)(ws + 3 * Hn * Cn * 2
                              + 2 * (size_t)Mrows * Hn * 2
                              + (size_t)Bn * Hn * Tn * 2); // 2560 x 1056 f32      (10.8 MB)

    const float qscale = 0.04508422002778011f;  // C^-0.5 * log2(e)
    convert_w3<<<768, 256, 0, stream>>>(Wq, Wk, Wv, wt, qscale);
    qkv_proj<<<512, 512, 0, stream>>>(x, wt, qk, vt);
    attn_fwd<<<Bn * UPB, 64, 0, stream>>>(qk, qk + (size_t)Mrows * Hn, vt, partial);
    attn_reduce<<<128 * Bn, 256, 0, stream>>>(partial, out);
}